// Round 7
// baseline (292.529 us; speedup 1.0000x reference)
//
#include <hip/hip_runtime.h>
#include <cstdint>
#include <cstddef>

#define N_NODES 100000
#define N_EDGES 1600000

#define NBK   391                          // ceil(100000/256) buckets of 256 nodes
#define NPB   128                          // partition blocks
#define EPB   ((N_EDGES + NPB - 1) / NPB)  // 12500 edges per partition block
#define NSLOT (NBK * NPB)                  // 50048 (bucket-major: slot = b*NPB + bid)
#define SCH   ((NSLOT + 1023) / 1024)      // 49 slots per scan thread
#define ES_CAP (N_EDGES + NBK * 2048 + 64) // padded edge-list capacity

typedef __attribute__((ext_vector_type(8))) short bf16x8;
typedef __attribute__((ext_vector_type(4))) float f32x4;

__device__ __forceinline__ float b2f(unsigned short u) {
    return __uint_as_float(((unsigned)u) << 16);
}
__device__ __forceinline__ unsigned short f2b(float f) {
    unsigned x = __float_as_uint(f);
    return (unsigned short)((x + 0x7FFFu + ((x >> 16) & 1u)) >> 16);
}

// split f32 -> bf16 hi (trunc) + bf16 lo (trunc of exact residual)
__device__ __forceinline__ void split8(const float4& a0, const float4& a1,
                                       bf16x8& hi, bf16x8& lo) {
    float f[8] = {a0.x, a0.y, a0.z, a0.w, a1.x, a1.y, a1.z, a1.w};
#pragma unroll
    for (int j = 0; j < 8; ++j) {
        unsigned u = __float_as_uint(f[j]);
        hi[j] = (short)(u >> 16);
        float l = f[j] - __uint_as_float(u & 0xFFFF0000u);   // exact
        lo[j] = (short)(__float_as_uint(l) >> 16);
    }
}

// ---------------- build: bucket partition with private sub-regions ----------------

// also zeroes the sentinel rows (row N_NODES) of both bf16 operand buffers (block 0)
__global__ __launch_bounds__(256) void k_hist(const int* __restrict__ dst,
                                              int* __restrict__ gcnt,
                                              unsigned short* __restrict__ hwb1,
                                              unsigned short* __restrict__ hwb2, int E) {
    __shared__ int lh[NBK];
    int t = threadIdx.x, bid = blockIdx.x;
    if (bid == 0) {
        if (t < 64) hwb1[(size_t)N_NODES * 64 + t] = 0;
        else if (t < 96) hwb2[(size_t)N_NODES * 32 + (t - 64)] = 0;
    }
    for (int i = t; i < NBK; i += 256) lh[i] = 0;
    __syncthreads();
    int e0 = bid * EPB, e1 = min(E, e0 + EPB);
    for (int e = e0 + t; e < e1; e += 256) atomicAdd(&lh[dst[e] >> 8], 1);
    __syncthreads();
    for (int b = t; b < NBK; b += 256) gcnt[b * NPB + bid] = lh[b];
}

// single-block exclusive scan over NSLOT counts (in place)
__global__ __launch_bounds__(1024) void k_scan1(int* __restrict__ g) {
    __shared__ int s[1024];
    int t = threadIdx.x;
    int base = t * SCH;
    int sum = 0;
    for (int j = 0; j < SCH; ++j) {
        int i = base + j;
        if (i < NSLOT) sum += g[i];
    }
    s[t] = sum;
    __syncthreads();
    for (int o = 1; o < 1024; o <<= 1) {
        int a = (t >= o) ? s[t - o] : 0;
        __syncthreads();
        s[t] += a;
        __syncthreads();
    }
    int excl = s[t] - sum;
    for (int j = 0; j < SCH; ++j) {
        int i = base + j;
        if (i < NSLOT) { int x = g[i]; g[i] = excl; excl += x; }
    }
}

__global__ __launch_bounds__(256) void k_partition(const int* __restrict__ src,
                                                   const int* __restrict__ dst,
                                                   const int* __restrict__ base,
                                                   unsigned* __restrict__ ebuf, int E) {
    __shared__ int lcur[NBK];
    int t = threadIdx.x, bid = blockIdx.x;
    for (int b = t; b < NBK; b += 256) lcur[b] = base[b * NPB + bid];
    __syncthreads();
    int e0 = bid * EPB, e1 = min(E, e0 + EPB);
    for (int e = e0 + t; e < e1; e += 256) {
        int d = dst[e];
        int b = d >> 8;
        int p = atomicAdd(&lcur[b], 1);
        ebuf[p] = (unsigned)src[e] | ((unsigned)(d & 255) << 20);
    }
}

// one block per bucket: per-node count/scan/place in LDS -> 8-padded per-node CSR.
__global__ __launch_bounds__(256) void k_bucket_csr(const int* __restrict__ base,
                                                    const unsigned* __restrict__ ebuf,
                                                    int* __restrict__ cnt,
                                                    float* __restrict__ dinv,
                                                    int* __restrict__ off,
                                                    int* __restrict__ es, int n) {
    __shared__ int lc[256];
    __shared__ int ss[256];
    __shared__ int lo[256];
    __shared__ int lcur[256];
    int b = blockIdx.x, t = threadIdx.x;
    int rstart = base[b * NPB];
    int rend = (b == NBK - 1) ? N_EDGES : base[(b + 1) * NPB];
    int wstart = ((rstart + 7) & ~7) + b * 2048;   // 8-aligned private write region
    lc[t] = 0;
    __syncthreads();
    for (int e = rstart + t; e < rend; e += 256) atomicAdd(&lc[(int)(ebuf[e] >> 20)], 1);
    __syncthreads();
    int v = lc[t];               // real degree
    int vp = (v + 7) & ~7;       // padded to multiple of 8
    ss[t] = vp;
    __syncthreads();
    for (int o = 1; o < 256; o <<= 1) {
        int a = (t >= o) ? ss[t - o] : 0;
        __syncthreads();
        ss[t] += a;
        __syncthreads();
    }
    lo[t] = ss[t] - vp;
    lcur[t] = 0;
    int node = b * 256 + t;
    if (node < n) {
        cnt[node] = vp;
        dinv[node] = rsqrtf((float)v + 1.0f);
        off[node] = wstart + lo[t];
    }
    __syncthreads();
    for (int e = rstart + t; e < rend; e += 256) {
        unsigned u = ebuf[e];
        int l = (int)(u >> 20);
        int p = atomicAdd(&lcur[l], 1);
        es[wstart + lo[l] + p] = (int)(u & 0xFFFFFu);
    }
    for (int q = v; q < vp; ++q) es[wstart + lo[t] + q] = N_NODES;
}

// ---------------- GEMM1 (MFMA hi/lo): hwb1 = bf16( dinv * (x[M,256] @ w1[256,64]) ) ----

__global__ __launch_bounds__(256) void k_gemm1_mfma(const float* __restrict__ x,
                                                    const float* __restrict__ w,
                                                    const float* __restrict__ dinv,
                                                    unsigned short* __restrict__ out, int M) {
    __shared__ unsigned short Bhi[32 * 64 * 8];   // 32 KB
    __shared__ unsigned short Blo[32 * 64 * 8];   // 32 KB
    int t = threadIdx.x;
    int wave = t >> 6, lane = t & 63;

    {
        int c = t & 63;
        int kg0 = t >> 6;
#pragma unroll
        for (int i = 0; i < 8; ++i) {
            int kgrp = kg0 + i * 4;
            bf16x8 h8, l8;
#pragma unroll
            for (int j = 0; j < 8; ++j) {
                float f = w[(size_t)(kgrp * 8 + j) * 64 + c];
                unsigned u = __float_as_uint(f);
                h8[j] = (short)(u >> 16);
                float l = f - __uint_as_float(u & 0xFFFF0000u);
                l8[j] = (short)(__float_as_uint(l) >> 16);
            }
            *(bf16x8*)&Bhi[(kgrp * 64 + c) * 8] = h8;
            *(bf16x8*)&Blo[(kgrp * 64 + c) * 8] = l8;
        }
    }
    __syncthreads();

    int row0w = blockIdx.x * 64 + wave * 16;
    int r = row0w + (lane & 15); if (r >= M) r = M - 1;
    const float* xr = x + (size_t)r * 256 + (lane >> 4) * 8;

    f32x4 acc[4] = {{0.f,0.f,0.f,0.f},{0.f,0.f,0.f,0.f},{0.f,0.f,0.f,0.f},{0.f,0.f,0.f,0.f}};

#pragma unroll
    for (int kf = 0; kf < 8; ++kf) {
        float4 a0 = *(const float4*)(xr + kf * 32);
        float4 a1 = *(const float4*)(xr + kf * 32 + 4);
        bf16x8 ahi, alo;
        split8(a0, a1, ahi, alo);
        int kgrpR = kf * 4 + (lane >> 4);
#pragma unroll
        for (int cf = 0; cf < 4; ++cf) {
            bf16x8 bhi = *(const bf16x8*)&Bhi[(kgrpR * 64 + cf * 16 + (lane & 15)) * 8];
            bf16x8 blo = *(const bf16x8*)&Blo[(kgrpR * 64 + cf * 16 + (lane & 15)) * 8];
            acc[cf] = __builtin_amdgcn_mfma_f32_16x16x32_bf16(ahi, bhi, acc[cf], 0, 0, 0);
            acc[cf] = __builtin_amdgcn_mfma_f32_16x16x32_bf16(ahi, blo, acc[cf], 0, 0, 0);
            acc[cf] = __builtin_amdgcn_mfma_f32_16x16x32_bf16(alo, bhi, acc[cf], 0, 0, 0);
        }
    }

#pragma unroll
    for (int j = 0; j < 4; ++j) {
        int rr = row0w + (lane >> 4) * 4 + j;
        if (rr < M) {
            float s = dinv[rr];
#pragma unroll
            for (int cf = 0; cf < 4; ++cf)
                out[(size_t)rr * 64 + cf * 16 + (lane & 15)] = f2b(acc[cf][j] * s);
        }
    }
}

// ---------------- GEMM2 (MFMA hi/lo): hwb2 = bf16( dinv * (h1[M,64] @ w2[64,32]) ) -----

__global__ __launch_bounds__(256) void k_gemm2_mfma(const float* __restrict__ h,
                                                    const float* __restrict__ w,
                                                    const float* __restrict__ dinv,
                                                    unsigned short* __restrict__ out, int M) {
    __shared__ unsigned short Bhi[8 * 32 * 8];   // 4 KB
    __shared__ unsigned short Blo[8 * 32 * 8];   // 4 KB
    int t = threadIdx.x;
    int wave = t >> 6, lane = t & 63;

    {
        int c = t & 31;
        int kg = t >> 5;
        bf16x8 h8, l8;
#pragma unroll
        for (int j = 0; j < 8; ++j) {
            float f = w[(size_t)(kg * 8 + j) * 32 + c];
            unsigned u = __float_as_uint(f);
            h8[j] = (short)(u >> 16);
            float l = f - __uint_as_float(u & 0xFFFF0000u);
            l8[j] = (short)(__float_as_uint(l) >> 16);
        }
        *(bf16x8*)&Bhi[(kg * 32 + c) * 8] = h8;
        *(bf16x8*)&Blo[(kg * 32 + c) * 8] = l8;
    }
    __syncthreads();

    int row0w = blockIdx.x * 64 + wave * 16;
    int r = row0w + (lane & 15); if (r >= M) r = M - 1;
    const float* xr = h + (size_t)r * 64 + (lane >> 4) * 8;

    f32x4 acc[2] = {{0.f,0.f,0.f,0.f},{0.f,0.f,0.f,0.f}};

#pragma unroll
    for (int kf = 0; kf < 2; ++kf) {
        float4 a0 = *(const float4*)(xr + kf * 32);
        float4 a1 = *(const float4*)(xr + kf * 32 + 4);
        bf16x8 ahi, alo;
        split8(a0, a1, ahi, alo);
        int kgrpR = kf * 4 + (lane >> 4);
#pragma unroll
        for (int cf = 0; cf < 2; ++cf) {
            bf16x8 bhi = *(const bf16x8*)&Bhi[(kgrpR * 32 + cf * 16 + (lane & 15)) * 8];
            bf16x8 blo = *(const bf16x8*)&Blo[(kgrpR * 32 + cf * 16 + (lane & 15)) * 8];
            acc[cf] = __builtin_amdgcn_mfma_f32_16x16x32_bf16(ahi, bhi, acc[cf], 0, 0, 0);
            acc[cf] = __builtin_amdgcn_mfma_f32_16x16x32_bf16(ahi, blo, acc[cf], 0, 0, 0);
            acc[cf] = __builtin_amdgcn_mfma_f32_16x16x32_bf16(alo, bhi, acc[cf], 0, 0, 0);
        }
    }

#pragma unroll
    for (int j = 0; j < 4; ++j) {
        int rr = row0w + (lane >> 4) * 4 + j;
        if (rr < M) {
            float s = dinv[rr];
#pragma unroll
            for (int cf = 0; cf < 2; ++cf)
                out[(size_t)rr * 32 + cf * 16 + (lane & 15)] = f2b(acc[cf][j] * s);
        }
    }
}

// ---------------- agg layer 1: wave-per-node, vectorized gather (4 edges/wave-load) ----
// quarter q = lane>>4 handles edge j+q; lane holds channels sub*4..sub*4+3 (8B)

__global__ __launch_bounds__(256) void k_agg1(const unsigned short* __restrict__ hwb,
                                              const float* __restrict__ dinv,
                                              const int* __restrict__ cnt,
                                              const int* __restrict__ off,
                                              const int* __restrict__ es,
                                              const float* __restrict__ bias,
                                              float* __restrict__ hout) {
    int gid = blockIdx.x * 256 + threadIdx.x;
    int node = gid >> 6;
    int lane = threadIdx.x & 63;
    int q = lane >> 4;
    int sub = lane & 15;
    const int* ep = es + off[node];
    int mp = cnt[node];
    const unsigned short* hb = hwb + sub * 4;

    float4 acc0 = {0.f, 0.f, 0.f, 0.f};
    float4 acc1 = {0.f, 0.f, 0.f, 0.f};
    for (int j = 0; j < mp; j += 8) {
        int sA = ep[j + q];
        int sB = ep[j + 4 + q];
        uint2 uA = *(const uint2*)(hb + (size_t)sA * 64);
        uint2 uB = *(const uint2*)(hb + (size_t)sB * 64);
        acc0.x += __uint_as_float(uA.x << 16);
        acc0.y += __uint_as_float(uA.x & 0xFFFF0000u);
        acc0.z += __uint_as_float(uA.y << 16);
        acc0.w += __uint_as_float(uA.y & 0xFFFF0000u);
        acc1.x += __uint_as_float(uB.x << 16);
        acc1.y += __uint_as_float(uB.x & 0xFFFF0000u);
        acc1.z += __uint_as_float(uB.y << 16);
        acc1.w += __uint_as_float(uB.y & 0xFFFF0000u);
    }
    float ax = acc0.x + acc1.x;
    float ay = acc0.y + acc1.y;
    float az = acc0.z + acc1.z;
    float aw = acc0.w + acc1.w;
    ax += __shfl_xor(ax, 16); ax += __shfl_xor(ax, 32);
    ay += __shfl_xor(ay, 16); ay += __shfl_xor(ay, 32);
    az += __shfl_xor(az, 16); az += __shfl_xor(az, 32);
    aw += __shfl_xor(aw, 16); aw += __shfl_xor(aw, 32);
    if (q == 0) {
        uint2 us = *(const uint2*)(hb + (size_t)node * 64);   // self (pre-scaled)
        ax += __uint_as_float(us.x << 16);
        ay += __uint_as_float(us.x & 0xFFFF0000u);
        az += __uint_as_float(us.y << 16);
        aw += __uint_as_float(us.y & 0xFFFF0000u);
        float dn = dinv[node];
        float4 bb = *(const float4*)&bias[sub * 4];
        float4 r;
        r.x = fmaxf(fmaf(dn, ax, bb.x), 0.0f);
        r.y = fmaxf(fmaf(dn, ay, bb.y), 0.0f);
        r.z = fmaxf(fmaf(dn, az, bb.z), 0.0f);
        r.w = fmaxf(fmaf(dn, aw, bb.w), 0.0f);
        *(float4*)&hout[(size_t)node * 64 + sub * 4] = r;
    }
}

// ---------------- agg layer 2 (vectorized, 8 edges/wave-load) + fused MLP head --------
// wave per node; octet o = lane>>3 handles edge j+o; lane holds channels sub*4..+3

__global__ __launch_bounds__(256) void k_agg2_mlp(const unsigned short* __restrict__ hwb,
                                                  const float* __restrict__ dinv,
                                                  const int* __restrict__ cnt,
                                                  const int* __restrict__ off,
                                                  const int* __restrict__ es,
                                                  const float* __restrict__ bias2,
                                                  const float* __restrict__ wf1,
                                                  const float* __restrict__ bf1,
                                                  const float* __restrict__ wf2,
                                                  const float* __restrict__ bf2,
                                                  float* __restrict__ out) {
    __shared__ float hs[4][36];
    __shared__ float W1[512];
    __shared__ float B1[16];
    __shared__ float W2[16];
    int t = threadIdx.x;
    W1[t] = wf1[t];
    W1[t + 256] = wf1[t + 256];
    if (t < 16) { B1[t] = bf1[t]; W2[t] = wf2[t]; }

    int wv = t >> 6;                  // local node 0..3
    int lane = t & 63;
    int o = lane >> 3;
    int sub = lane & 7;
    int node = blockIdx.x * 4 + wv;
    const int* ep = es + off[node];
    int mp = cnt[node];
    const unsigned short* hb = hwb + sub * 4;

    float4 acc = {0.f, 0.f, 0.f, 0.f};
    for (int j = 0; j < mp; j += 8) {
        int s = ep[j + o];
        uint2 u = *(const uint2*)(hb + (size_t)s * 32);
        acc.x += __uint_as_float(u.x << 16);
        acc.y += __uint_as_float(u.x & 0xFFFF0000u);
        acc.z += __uint_as_float(u.y << 16);
        acc.w += __uint_as_float(u.y & 0xFFFF0000u);
    }
    acc.x += __shfl_xor(acc.x, 8); acc.x += __shfl_xor(acc.x, 16); acc.x += __shfl_xor(acc.x, 32);
    acc.y += __shfl_xor(acc.y, 8); acc.y += __shfl_xor(acc.y, 16); acc.y += __shfl_xor(acc.y, 32);
    acc.z += __shfl_xor(acc.z, 8); acc.z += __shfl_xor(acc.z, 16); acc.z += __shfl_xor(acc.z, 32);
    acc.w += __shfl_xor(acc.w, 8); acc.w += __shfl_xor(acc.w, 16); acc.w += __shfl_xor(acc.w, 32);
    if (o == 0) {
        uint2 us = *(const uint2*)(hb + (size_t)node * 32);
        acc.x += __uint_as_float(us.x << 16);
        acc.y += __uint_as_float(us.x & 0xFFFF0000u);
        acc.z += __uint_as_float(us.y << 16);
        acc.w += __uint_as_float(us.y & 0xFFFF0000u);
        float dn = dinv[node];
        float4 bb = *(const float4*)&bias2[sub * 4];
        hs[wv][sub * 4 + 0] = fmaxf(fmaf(dn, acc.x, bb.x), 0.0f);
        hs[wv][sub * 4 + 1] = fmaxf(fmaf(dn, acc.y, bb.y), 0.0f);
        hs[wv][sub * 4 + 2] = fmaxf(fmaf(dn, acc.z, bb.z), 0.0f);
        hs[wv][sub * 4 + 3] = fmaxf(fmaf(dn, acc.w, bb.w), 0.0f);
    }
    __syncthreads();
    if (t < 64) {
        int nn = t >> 4, jj = t & 15;
        float s = B1[jj];
#pragma unroll
        for (int k = 0; k < 32; ++k) s += hs[nn][k] * W1[k * 16 + jj];
        float p = fmaxf(s, 0.0f) * W2[jj];
        p += __shfl_xor(p, 1);
        p += __shfl_xor(p, 2);
        p += __shfl_xor(p, 4);
        p += __shfl_xor(p, 8);
        if (jj == 0) out[blockIdx.x * 4 + nn] = p + bf2[0];
    }
}

// ---------------- host ----------------

extern "C" void kernel_launch(void* const* d_in, const int* in_sizes, int n_in,
                              void* d_out, int out_size, void* d_ws, size_t ws_size,
                              hipStream_t stream) {
    const float* x   = (const float*)d_in[0];
    const int*   ei  = (const int*)d_in[1];
    const float* w1  = (const float*)d_in[2];
    const float* b1  = (const float*)d_in[3];
    const float* w2  = (const float*)d_in[4];
    const float* b2  = (const float*)d_in[5];
    const float* wf1 = (const float*)d_in[6];
    const float* bf1 = (const float*)d_in[7];
    const float* wf2 = (const float*)d_in[8];
    const float* bf2 = (const float*)d_in[9];

    const int n = N_NODES;
    const int E = N_EDGES;
    const int* srcp = ei;        // edge_index[0]
    const int* dstp = ei + E;    // edge_index[1]

    char* p = (char*)d_ws;
    auto take = [&](size_t bytes) {
        char* r = p;
        p += (bytes + 255) & ~(size_t)255;
        return r;
    };
    float* dinv = (float*)take((size_t)n * 4);
    int*   cnt  = (int*)take((size_t)n * 4);
    int*   off  = (int*)take((size_t)n * 4);
    int*   gcnt = (int*)take((size_t)NSLOT * 4);
    int*   es   = (int*)take((size_t)ES_CAP * 4);
    unsigned short* hwb1 = (unsigned short*)take((size_t)(n + 1) * 64 * 2);  // aliases ebuf
    unsigned short* hwb2 = (unsigned short*)take((size_t)(n + 1) * 32 * 2);
    float* h1   = (float*)take((size_t)n * 64 * 4);
    unsigned* ebuf = (unsigned*)hwb1;   // 6.4MB, consumed by k_bucket_csr before gemm1

    // build per-node padded CSR (bucketed two-phase, no global atomics)
    k_hist<<<NPB, 256, 0, stream>>>(dstp, gcnt, hwb1, hwb2, E);
    k_scan1<<<1, 1024, 0, stream>>>(gcnt);
    k_partition<<<NPB, 256, 0, stream>>>(srcp, dstp, gcnt, ebuf, E);
    k_bucket_csr<<<NBK, 256, 0, stream>>>(gcnt, ebuf, cnt, dinv, off, es, n);

    // GNN layers
    k_gemm1_mfma<<<(n + 63) / 64, 256, 0, stream>>>(x, w1, dinv, hwb1, n);
    k_agg1<<<(n * 64) / 256, 256, 0, stream>>>(hwb1, dinv, cnt, off, es, b1, h1);
    k_gemm2_mfma<<<(n + 63) / 64, 256, 0, stream>>>(h1, w2, dinv, hwb2, n);
    k_agg2_mlp<<<n / 4, 256, 0, stream>>>(hwb2, dinv, cnt, off, es, b2,
                                          wf1, bf1, wf2, bf2, (float*)d_out);
}

// Round 8
// 192.139 us; speedup vs baseline: 1.5225x; 1.5225x over previous
//
#include <hip/hip_runtime.h>
#include <cstdint>
#include <cstddef>

#define N_NODES 100000
#define N_EDGES 1600000

#define NBK   391                          // ceil(100000/256) buckets of 256 nodes
#define NPB   256                          // partition blocks
#define EPB   ((N_EDGES + NPB - 1) / NPB)  // 6250 edges per partition block
#define NSLOT (NBK * NPB)                  // 100096 (bucket-major: slot = b*NPB + bid)
#define NSB   ((NSLOT + 1023) / 1024)      // 98 scan blocks
#define ES_CAP (N_EDGES + NBK * 2048 + 64) // padded edge-list capacity

typedef __attribute__((ext_vector_type(8))) short bf16x8;
typedef __attribute__((ext_vector_type(4))) float f32x4;

__device__ __forceinline__ float b2f(unsigned short u) {
    return __uint_as_float(((unsigned)u) << 16);
}
__device__ __forceinline__ unsigned short f2b(float f) {
    unsigned x = __float_as_uint(f);
    return (unsigned short)((x + 0x7FFFu + ((x >> 16) & 1u)) >> 16);
}

// split f32 -> bf16 hi (trunc) + bf16 lo (trunc of exact residual)
__device__ __forceinline__ void split8(const float4& a0, const float4& a1,
                                       bf16x8& hi, bf16x8& lo) {
    float f[8] = {a0.x, a0.y, a0.z, a0.w, a1.x, a1.y, a1.z, a1.w};
#pragma unroll
    for (int j = 0; j < 8; ++j) {
        unsigned u = __float_as_uint(f[j]);
        hi[j] = (short)(u >> 16);
        float l = f[j] - __uint_as_float(u & 0xFFFF0000u);   // exact
        lo[j] = (short)(__float_as_uint(l) >> 16);
    }
}

// ---------------- build: bucket partition with private sub-regions ----------------

// also zeroes the sentinel rows (row N_NODES) of both bf16 operand buffers (block 0)
__global__ __launch_bounds__(256) void k_hist(const int* __restrict__ dst,
                                              int* __restrict__ gcnt,
                                              unsigned short* __restrict__ hwb1,
                                              unsigned short* __restrict__ hwb2, int E) {
    __shared__ int lh[NBK];
    int t = threadIdx.x, bid = blockIdx.x;
    if (bid == 0) {
        if (t < 64) hwb1[(size_t)N_NODES * 64 + t] = 0;
        else if (t < 96) hwb2[(size_t)N_NODES * 32 + (t - 64)] = 0;
    }
    for (int i = t; i < NBK; i += 256) lh[i] = 0;
    __syncthreads();
    int e0 = bid * EPB, e1 = min(E, e0 + EPB);
    for (int e = e0 + t; e < e1; e += 256) atomicAdd(&lh[dst[e] >> 8], 1);
    __syncthreads();
    for (int b = t; b < NBK; b += 256) gcnt[b * NPB + bid] = lh[b];
}

__global__ __launch_bounds__(1024) void k_scanA(int* __restrict__ g,
                                                int* __restrict__ bsum, int ntot) {
    __shared__ int s[1024];
    int t = threadIdx.x;
    int i = blockIdx.x * 1024 + t;
    int v = (i < ntot) ? g[i] : 0;
    s[t] = v;
    __syncthreads();
    for (int o = 1; o < 1024; o <<= 1) {
        int a = (t >= o) ? s[t - o] : 0;
        __syncthreads();
        s[t] += a;
        __syncthreads();
    }
    if (i < ntot) g[i] = s[t] - v;
    if (t == 1023) bsum[blockIdx.x] = s[1023];
}

__global__ __launch_bounds__(128) void k_scanB(int* __restrict__ bsum, int nb) {
    __shared__ int s[128];
    int t = threadIdx.x;
    int v = (t < nb) ? bsum[t] : 0;
    s[t] = v;
    __syncthreads();
    for (int o = 1; o < 128; o <<= 1) {
        int a = (t >= o) ? s[t - o] : 0;
        __syncthreads();
        s[t] += a;
        __syncthreads();
    }
    if (t < nb) bsum[t] = s[t] - v;
}

__global__ __launch_bounds__(1024) void k_scanC(int* __restrict__ g,
                                                const int* __restrict__ bsum, int ntot) {
    int i = blockIdx.x * 1024 + threadIdx.x;
    if (i < ntot) g[i] += bsum[blockIdx.x];
}

__global__ __launch_bounds__(256) void k_partition(const int* __restrict__ src,
                                                   const int* __restrict__ dst,
                                                   const int* __restrict__ base,
                                                   unsigned* __restrict__ ebuf, int E) {
    __shared__ int lcur[NBK];
    int t = threadIdx.x, bid = blockIdx.x;
    for (int b = t; b < NBK; b += 256) lcur[b] = base[b * NPB + bid];
    __syncthreads();
    int e0 = bid * EPB, e1 = min(E, e0 + EPB);
    for (int e = e0 + t; e < e1; e += 256) {
        int d = dst[e];
        int b = d >> 8;
        int p = atomicAdd(&lcur[b], 1);
        ebuf[p] = (unsigned)src[e] | ((unsigned)(d & 255) << 20);
    }
}

// one block per bucket: per-node count/scan/place in LDS -> 8-padded per-node CSR.
__global__ __launch_bounds__(256) void k_bucket_csr(const int* __restrict__ base,
                                                    const unsigned* __restrict__ ebuf,
                                                    int* __restrict__ cnt,
                                                    float* __restrict__ dinv,
                                                    int* __restrict__ off,
                                                    int* __restrict__ es, int n) {
    __shared__ int lc[256];
    __shared__ int ss[256];
    __shared__ int lo[256];
    __shared__ int lcur[256];
    int b = blockIdx.x, t = threadIdx.x;
    int rstart = base[b * NPB];
    int rend = (b == NBK - 1) ? N_EDGES : base[(b + 1) * NPB];
    int wstart = ((rstart + 7) & ~7) + b * 2048;   // 8-aligned private write region
    lc[t] = 0;
    __syncthreads();
    for (int e = rstart + t; e < rend; e += 256) atomicAdd(&lc[(int)(ebuf[e] >> 20)], 1);
    __syncthreads();
    int v = lc[t];               // real degree
    int vp = (v + 7) & ~7;       // padded to multiple of 8
    ss[t] = vp;
    __syncthreads();
    for (int o = 1; o < 256; o <<= 1) {
        int a = (t >= o) ? ss[t - o] : 0;
        __syncthreads();
        ss[t] += a;
        __syncthreads();
    }
    lo[t] = ss[t] - vp;
    lcur[t] = 0;
    int node = b * 256 + t;
    if (node < n) {
        cnt[node] = vp;
        dinv[node] = rsqrtf((float)v + 1.0f);
        off[node] = wstart + lo[t];
    }
    __syncthreads();
    for (int e = rstart + t; e < rend; e += 256) {
        unsigned u = ebuf[e];
        int l = (int)(u >> 20);
        int p = atomicAdd(&lcur[l], 1);
        es[wstart + lo[l] + p] = (int)(u & 0xFFFFFu);
    }
    for (int q = v; q < vp; ++q) es[wstart + lo[t] + q] = N_NODES;
}

// ---------------- GEMM1 (MFMA hi/lo): hwb1 = bf16( dinv * (x[M,256] @ w1[256,64]) ) ----

__global__ __launch_bounds__(256) void k_gemm1_mfma(const float* __restrict__ x,
                                                    const float* __restrict__ w,
                                                    const float* __restrict__ dinv,
                                                    unsigned short* __restrict__ out, int M) {
    __shared__ unsigned short Bhi[32 * 64 * 8];   // 32 KB
    __shared__ unsigned short Blo[32 * 64 * 8];   // 32 KB
    int t = threadIdx.x;
    int wave = t >> 6, lane = t & 63;

    {
        int c = t & 63;
        int kg0 = t >> 6;
#pragma unroll
        for (int i = 0; i < 8; ++i) {
            int kgrp = kg0 + i * 4;
            bf16x8 h8, l8;
#pragma unroll
            for (int j = 0; j < 8; ++j) {
                float f = w[(size_t)(kgrp * 8 + j) * 64 + c];
                unsigned u = __float_as_uint(f);
                h8[j] = (short)(u >> 16);
                float l = f - __uint_as_float(u & 0xFFFF0000u);
                l8[j] = (short)(__float_as_uint(l) >> 16);
            }
            *(bf16x8*)&Bhi[(kgrp * 64 + c) * 8] = h8;
            *(bf16x8*)&Blo[(kgrp * 64 + c) * 8] = l8;
        }
    }
    __syncthreads();

    int row0w = blockIdx.x * 64 + wave * 16;
    int r = row0w + (lane & 15); if (r >= M) r = M - 1;
    const float* xr = x + (size_t)r * 256 + (lane >> 4) * 8;

    f32x4 acc[4] = {{0.f,0.f,0.f,0.f},{0.f,0.f,0.f,0.f},{0.f,0.f,0.f,0.f},{0.f,0.f,0.f,0.f}};

#pragma unroll
    for (int kf = 0; kf < 8; ++kf) {
        float4 a0 = *(const float4*)(xr + kf * 32);
        float4 a1 = *(const float4*)(xr + kf * 32 + 4);
        bf16x8 ahi, alo;
        split8(a0, a1, ahi, alo);
        int kgrpR = kf * 4 + (lane >> 4);
#pragma unroll
        for (int cf = 0; cf < 4; ++cf) {
            bf16x8 bhi = *(const bf16x8*)&Bhi[(kgrpR * 64 + cf * 16 + (lane & 15)) * 8];
            bf16x8 blo = *(const bf16x8*)&Blo[(kgrpR * 64 + cf * 16 + (lane & 15)) * 8];
            acc[cf] = __builtin_amdgcn_mfma_f32_16x16x32_bf16(ahi, bhi, acc[cf], 0, 0, 0);
            acc[cf] = __builtin_amdgcn_mfma_f32_16x16x32_bf16(ahi, blo, acc[cf], 0, 0, 0);
            acc[cf] = __builtin_amdgcn_mfma_f32_16x16x32_bf16(alo, bhi, acc[cf], 0, 0, 0);
        }
    }

#pragma unroll
    for (int j = 0; j < 4; ++j) {
        int rr = row0w + (lane >> 4) * 4 + j;
        if (rr < M) {
            float s = dinv[rr];
#pragma unroll
            for (int cf = 0; cf < 4; ++cf)
                out[(size_t)rr * 64 + cf * 16 + (lane & 15)] = f2b(acc[cf][j] * s);
        }
    }
}

// ---------------- GEMM2 (MFMA hi/lo): hwb2 = bf16( dinv * (h1[M,64] @ w2[64,32]) ) -----

__global__ __launch_bounds__(256) void k_gemm2_mfma(const float* __restrict__ h,
                                                    const float* __restrict__ w,
                                                    const float* __restrict__ dinv,
                                                    unsigned short* __restrict__ out, int M) {
    __shared__ unsigned short Bhi[8 * 32 * 8];   // 4 KB
    __shared__ unsigned short Blo[8 * 32 * 8];   // 4 KB
    int t = threadIdx.x;
    int wave = t >> 6, lane = t & 63;

    {
        int c = t & 31;
        int kg = t >> 5;
        bf16x8 h8, l8;
#pragma unroll
        for (int j = 0; j < 8; ++j) {
            float f = w[(size_t)(kg * 8 + j) * 32 + c];
            unsigned u = __float_as_uint(f);
            h8[j] = (short)(u >> 16);
            float l = f - __uint_as_float(u & 0xFFFF0000u);
            l8[j] = (short)(__float_as_uint(l) >> 16);
        }
        *(bf16x8*)&Bhi[(kg * 32 + c) * 8] = h8;
        *(bf16x8*)&Blo[(kg * 32 + c) * 8] = l8;
    }
    __syncthreads();

    int row0w = blockIdx.x * 64 + wave * 16;
    int r = row0w + (lane & 15); if (r >= M) r = M - 1;
    const float* xr = h + (size_t)r * 64 + (lane >> 4) * 8;

    f32x4 acc[2] = {{0.f,0.f,0.f,0.f},{0.f,0.f,0.f,0.f}};

#pragma unroll
    for (int kf = 0; kf < 2; ++kf) {
        float4 a0 = *(const float4*)(xr + kf * 32);
        float4 a1 = *(const float4*)(xr + kf * 32 + 4);
        bf16x8 ahi, alo;
        split8(a0, a1, ahi, alo);
        int kgrpR = kf * 4 + (lane >> 4);
#pragma unroll
        for (int cf = 0; cf < 2; ++cf) {
            bf16x8 bhi = *(const bf16x8*)&Bhi[(kgrpR * 32 + cf * 16 + (lane & 15)) * 8];
            bf16x8 blo = *(const bf16x8*)&Blo[(kgrpR * 32 + cf * 16 + (lane & 15)) * 8];
            acc[cf] = __builtin_amdgcn_mfma_f32_16x16x32_bf16(ahi, bhi, acc[cf], 0, 0, 0);
            acc[cf] = __builtin_amdgcn_mfma_f32_16x16x32_bf16(ahi, blo, acc[cf], 0, 0, 0);
            acc[cf] = __builtin_amdgcn_mfma_f32_16x16x32_bf16(alo, bhi, acc[cf], 0, 0, 0);
        }
    }

#pragma unroll
    for (int j = 0; j < 4; ++j) {
        int rr = row0w + (lane >> 4) * 4 + j;
        if (rr < M) {
            float s = dinv[rr];
#pragma unroll
            for (int cf = 0; cf < 2; ++cf)
                out[(size_t)rr * 32 + cf * 16 + (lane & 15)] = f2b(acc[cf][j] * s);
        }
    }
}

// ---------------- agg layer 1: wave-per-node, vectorized gather (4 edges/wave-load) ----
// quarter q = lane>>4 handles edge j+q; lane holds channels sub*4..sub*4+3 (8B)

__global__ __launch_bounds__(256) void k_agg1(const unsigned short* __restrict__ hwb,
                                              const float* __restrict__ dinv,
                                              const int* __restrict__ cnt,
                                              const int* __restrict__ off,
                                              const int* __restrict__ es,
                                              const float* __restrict__ bias,
                                              float* __restrict__ hout) {
    int gid = blockIdx.x * 256 + threadIdx.x;
    int node = gid >> 6;
    int lane = threadIdx.x & 63;
    int q = lane >> 4;
    int sub = lane & 15;
    const int* ep = es + off[node];
    int mp = cnt[node];
    const unsigned short* hb = hwb + sub * 4;

    float4 acc0 = {0.f, 0.f, 0.f, 0.f};
    float4 acc1 = {0.f, 0.f, 0.f, 0.f};
    for (int j = 0; j < mp; j += 8) {
        int sA = ep[j + q];
        int sB = ep[j + 4 + q];
        uint2 uA = *(const uint2*)(hb + (size_t)sA * 64);
        uint2 uB = *(const uint2*)(hb + (size_t)sB * 64);
        acc0.x += __uint_as_float(uA.x << 16);
        acc0.y += __uint_as_float(uA.x & 0xFFFF0000u);
        acc0.z += __uint_as_float(uA.y << 16);
        acc0.w += __uint_as_float(uA.y & 0xFFFF0000u);
        acc1.x += __uint_as_float(uB.x << 16);
        acc1.y += __uint_as_float(uB.x & 0xFFFF0000u);
        acc1.z += __uint_as_float(uB.y << 16);
        acc1.w += __uint_as_float(uB.y & 0xFFFF0000u);
    }
    float ax = acc0.x + acc1.x;
    float ay = acc0.y + acc1.y;
    float az = acc0.z + acc1.z;
    float aw = acc0.w + acc1.w;
    ax += __shfl_xor(ax, 16); ax += __shfl_xor(ax, 32);
    ay += __shfl_xor(ay, 16); ay += __shfl_xor(ay, 32);
    az += __shfl_xor(az, 16); az += __shfl_xor(az, 32);
    aw += __shfl_xor(aw, 16); aw += __shfl_xor(aw, 32);
    if (q == 0) {
        uint2 us = *(const uint2*)(hb + (size_t)node * 64);   // self (pre-scaled)
        ax += __uint_as_float(us.x << 16);
        ay += __uint_as_float(us.x & 0xFFFF0000u);
        az += __uint_as_float(us.y << 16);
        aw += __uint_as_float(us.y & 0xFFFF0000u);
        float dn = dinv[node];
        float4 bb = *(const float4*)&bias[sub * 4];
        float4 r;
        r.x = fmaxf(fmaf(dn, ax, bb.x), 0.0f);
        r.y = fmaxf(fmaf(dn, ay, bb.y), 0.0f);
        r.z = fmaxf(fmaf(dn, az, bb.z), 0.0f);
        r.w = fmaxf(fmaf(dn, aw, bb.w), 0.0f);
        *(float4*)&hout[(size_t)node * 64 + sub * 4] = r;
    }
}

// ---------------- agg layer 2 (vectorized, 8 edges/wave-load) + fused MLP head --------

__global__ __launch_bounds__(256) void k_agg2_mlp(const unsigned short* __restrict__ hwb,
                                                  const float* __restrict__ dinv,
                                                  const int* __restrict__ cnt,
                                                  const int* __restrict__ off,
                                                  const int* __restrict__ es,
                                                  const float* __restrict__ bias2,
                                                  const float* __restrict__ wf1,
                                                  const float* __restrict__ bf1,
                                                  const float* __restrict__ wf2,
                                                  const float* __restrict__ bf2,
                                                  float* __restrict__ out) {
    __shared__ float hs[4][36];
    __shared__ float W1[512];
    __shared__ float B1[16];
    __shared__ float W2[16];
    int t = threadIdx.x;
    W1[t] = wf1[t];
    W1[t + 256] = wf1[t + 256];
    if (t < 16) { B1[t] = bf1[t]; W2[t] = wf2[t]; }

    int wv = t >> 6;                  // local node 0..3
    int lane = t & 63;
    int o = lane >> 3;
    int sub = lane & 7;
    int node = blockIdx.x * 4 + wv;
    const int* ep = es + off[node];
    int mp = cnt[node];
    const unsigned short* hb = hwb + sub * 4;

    float4 acc = {0.f, 0.f, 0.f, 0.f};
    for (int j = 0; j < mp; j += 8) {
        int s = ep[j + o];
        uint2 u = *(const uint2*)(hb + (size_t)s * 32);
        acc.x += __uint_as_float(u.x << 16);
        acc.y += __uint_as_float(u.x & 0xFFFF0000u);
        acc.z += __uint_as_float(u.y << 16);
        acc.w += __uint_as_float(u.y & 0xFFFF0000u);
    }
    acc.x += __shfl_xor(acc.x, 8); acc.x += __shfl_xor(acc.x, 16); acc.x += __shfl_xor(acc.x, 32);
    acc.y += __shfl_xor(acc.y, 8); acc.y += __shfl_xor(acc.y, 16); acc.y += __shfl_xor(acc.y, 32);
    acc.z += __shfl_xor(acc.z, 8); acc.z += __shfl_xor(acc.z, 16); acc.z += __shfl_xor(acc.z, 32);
    acc.w += __shfl_xor(acc.w, 8); acc.w += __shfl_xor(acc.w, 16); acc.w += __shfl_xor(acc.w, 32);
    if (o == 0) {
        uint2 us = *(const uint2*)(hb + (size_t)node * 32);
        acc.x += __uint_as_float(us.x << 16);
        acc.y += __uint_as_float(us.x & 0xFFFF0000u);
        acc.z += __uint_as_float(us.y << 16);
        acc.w += __uint_as_float(us.y & 0xFFFF0000u);
        float dn = dinv[node];
        float4 bb = *(const float4*)&bias2[sub * 4];
        hs[wv][sub * 4 + 0] = fmaxf(fmaf(dn, acc.x, bb.x), 0.0f);
        hs[wv][sub * 4 + 1] = fmaxf(fmaf(dn, acc.y, bb.y), 0.0f);
        hs[wv][sub * 4 + 2] = fmaxf(fmaf(dn, acc.z, bb.z), 0.0f);
        hs[wv][sub * 4 + 3] = fmaxf(fmaf(dn, acc.w, bb.w), 0.0f);
    }
    __syncthreads();
    if (t < 64) {
        int nn = t >> 4, jj = t & 15;
        float s = B1[jj];
#pragma unroll
        for (int k = 0; k < 32; ++k) s += hs[nn][k] * W1[k * 16 + jj];
        float p = fmaxf(s, 0.0f) * W2[jj];
        p += __shfl_xor(p, 1);
        p += __shfl_xor(p, 2);
        p += __shfl_xor(p, 4);
        p += __shfl_xor(p, 8);
        if (jj == 0) out[blockIdx.x * 4 + nn] = p + bf2[0];
    }
}

// ---------------- host ----------------

extern "C" void kernel_launch(void* const* d_in, const int* in_sizes, int n_in,
                              void* d_out, int out_size, void* d_ws, size_t ws_size,
                              hipStream_t stream) {
    const float* x   = (const float*)d_in[0];
    const int*   ei  = (const int*)d_in[1];
    const float* w1  = (const float*)d_in[2];
    const float* b1  = (const float*)d_in[3];
    const float* w2  = (const float*)d_in[4];
    const float* b2  = (const float*)d_in[5];
    const float* wf1 = (const float*)d_in[6];
    const float* bf1 = (const float*)d_in[7];
    const float* wf2 = (const float*)d_in[8];
    const float* bf2 = (const float*)d_in[9];

    const int n = N_NODES;
    const int E = N_EDGES;
    const int* srcp = ei;        // edge_index[0]
    const int* dstp = ei + E;    // edge_index[1]

    char* p = (char*)d_ws;
    auto take = [&](size_t bytes) {
        char* r = p;
        p += (bytes + 255) & ~(size_t)255;
        return r;
    };
    float* dinv = (float*)take((size_t)n * 4);
    int*   cnt  = (int*)take((size_t)n * 4);
    int*   off  = (int*)take((size_t)n * 4);
    int*   gcnt = (int*)take((size_t)NSLOT * 4);
    int*   bsum = (int*)take(512);
    int*   es   = (int*)take((size_t)ES_CAP * 4);
    unsigned short* hwb1 = (unsigned short*)take((size_t)(n + 1) * 64 * 2);  // aliases ebuf
    unsigned short* hwb2 = (unsigned short*)take((size_t)(n + 1) * 32 * 2);
    float* h1   = (float*)take((size_t)n * 64 * 4);
    unsigned* ebuf = (unsigned*)hwb1;   // 6.4MB, consumed by k_bucket_csr before gemm1

    // build per-node padded CSR (bucketed two-phase, no global atomics)
    k_hist<<<NPB, 256, 0, stream>>>(dstp, gcnt, hwb1, hwb2, E);
    k_scanA<<<NSB, 1024, 0, stream>>>(gcnt, bsum, NSLOT);
    k_scanB<<<1, 128, 0, stream>>>(bsum, NSB);
    k_scanC<<<NSB, 1024, 0, stream>>>(gcnt, bsum, NSLOT);
    k_partition<<<NPB, 256, 0, stream>>>(srcp, dstp, gcnt, ebuf, E);
    k_bucket_csr<<<NBK, 256, 0, stream>>>(gcnt, ebuf, cnt, dinv, off, es, n);

    // GNN layers
    k_gemm1_mfma<<<(n + 63) / 64, 256, 0, stream>>>(x, w1, dinv, hwb1, n);
    k_agg1<<<(n * 64) / 256, 256, 0, stream>>>(hwb1, dinv, cnt, off, es, b1, h1);
    k_gemm2_mfma<<<(n + 63) / 64, 256, 0, stream>>>(h1, w2, dinv, hwb2, n);
    k_agg2_mlp<<<n / 4, 256, 0, stream>>>(hwb2, dinv, cnt, off, es, b2,
                                          wf1, bf1, wf2, bf2, (float*)d_out);
}

// Round 9
// 164.209 us; speedup vs baseline: 1.7814x; 1.1701x over previous
//
#include <hip/hip_runtime.h>
#include <cstdint>
#include <cstddef>

#define N_NODES 100000
#define N_EDGES 1600000

#define NBK   391                          // ceil(100000/256) buckets of 256 nodes
#define NPB   256                          // partition blocks
#define EPB   ((N_EDGES + NPB - 1) / NPB)  // 6250 edges per partition block
#define NSLOT (NBK * NPB)                  // 100096 (bucket-major: slot = b*NPB + bid)
#define NSB   ((NSLOT + 1023) / 1024)      // 98 scan blocks
#define ES_CAP (N_EDGES + NBK * 2048 + 64) // padded edge-list capacity

typedef __attribute__((ext_vector_type(8))) short bf16x8;
typedef __attribute__((ext_vector_type(4))) float f32x4;

__device__ __forceinline__ float b2f(unsigned short u) {
    return __uint_as_float(((unsigned)u) << 16);
}
__device__ __forceinline__ unsigned short f2b(float f) {
    unsigned x = __float_as_uint(f);
    return (unsigned short)((x + 0x7FFFu + ((x >> 16) & 1u)) >> 16);
}

// split 8 f32 -> bf16 hi (trunc) + bf16 lo (trunc of exact residual)
__device__ __forceinline__ void split8a(const float* f, bf16x8& hi, bf16x8& lo) {
#pragma unroll
    for (int j = 0; j < 8; ++j) {
        unsigned u = __float_as_uint(f[j]);
        hi[j] = (short)(u >> 16);
        float l = f[j] - __uint_as_float(u & 0xFFFF0000u);   // exact
        lo[j] = (short)(__float_as_uint(l) >> 16);
    }
}
__device__ __forceinline__ void split8(const float4& a0, const float4& a1,
                                       bf16x8& hi, bf16x8& lo) {
    float f[8] = {a0.x, a0.y, a0.z, a0.w, a1.x, a1.y, a1.z, a1.w};
    split8a(f, hi, lo);
}

// ---------------- build: bucket partition with private sub-regions ----------------

// also zeroes the sentinel rows (row N_NODES) of both bf16 operand buffers (block 0)
__global__ __launch_bounds__(256) void k_hist(const int* __restrict__ dst,
                                              int* __restrict__ gcnt,
                                              unsigned short* __restrict__ hwb1,
                                              unsigned short* __restrict__ hwb2, int E) {
    __shared__ int lh[NBK];
    int t = threadIdx.x, bid = blockIdx.x;
    if (bid == 0) {
        if (t < 64) hwb1[(size_t)N_NODES * 64 + t] = 0;
        else if (t < 96) hwb2[(size_t)N_NODES * 32 + (t - 64)] = 0;
    }
    for (int i = t; i < NBK; i += 256) lh[i] = 0;
    __syncthreads();
    int e0 = bid * EPB, e1 = min(E, e0 + EPB);
    for (int e = e0 + t; e < e1; e += 256) atomicAdd(&lh[dst[e] >> 8], 1);
    __syncthreads();
    for (int b = t; b < NBK; b += 256) gcnt[b * NPB + bid] = lh[b];
}

__global__ __launch_bounds__(1024) void k_scanA(int* __restrict__ g,
                                                int* __restrict__ bsum, int ntot) {
    __shared__ int s[1024];
    int t = threadIdx.x;
    int i = blockIdx.x * 1024 + t;
    int v = (i < ntot) ? g[i] : 0;
    s[t] = v;
    __syncthreads();
    for (int o = 1; o < 1024; o <<= 1) {
        int a = (t >= o) ? s[t - o] : 0;
        __syncthreads();
        s[t] += a;
        __syncthreads();
    }
    if (i < ntot) g[i] = s[t] - v;
    if (t == 1023) bsum[blockIdx.x] = s[1023];
}

// adds this block's exclusive prefix of bsum (computed in-block) to each element
__global__ __launch_bounds__(1024) void k_scanC(int* __restrict__ g,
                                                const int* __restrict__ bsum, int ntot) {
    __shared__ int sp[1024];
    int t = threadIdx.x;
    sp[t] = (t < blockIdx.x && t < NSB) ? bsum[t] : 0;
    __syncthreads();
    for (int o = 512; o > 0; o >>= 1) {
        if (t < o) sp[t] += sp[t + o];
        __syncthreads();
    }
    int pref = sp[0];
    int i = blockIdx.x * 1024 + t;
    if (i < ntot) g[i] += pref;
}

__global__ __launch_bounds__(256) void k_partition(const int* __restrict__ src,
                                                   const int* __restrict__ dst,
                                                   const int* __restrict__ base,
                                                   unsigned* __restrict__ ebuf, int E) {
    __shared__ int lcur[NBK];
    int t = threadIdx.x, bid = blockIdx.x;
    for (int b = t; b < NBK; b += 256) lcur[b] = base[b * NPB + bid];
    __syncthreads();
    int e0 = bid * EPB, e1 = min(E, e0 + EPB);
    for (int e = e0 + t; e < e1; e += 256) {
        int d = dst[e];
        int b = d >> 8;
        int p = atomicAdd(&lcur[b], 1);
        ebuf[p] = (unsigned)src[e] | ((unsigned)(d & 255) << 20);
    }
}

// one block per bucket: per-node count/scan/place in LDS -> 8-padded per-node CSR.
__global__ __launch_bounds__(256) void k_bucket_csr(const int* __restrict__ base,
                                                    const unsigned* __restrict__ ebuf,
                                                    int* __restrict__ cnt,
                                                    float* __restrict__ dinv,
                                                    int* __restrict__ off,
                                                    int* __restrict__ es, int n) {
    __shared__ int lc[256];
    __shared__ int ss[256];
    __shared__ int lo[256];
    __shared__ int lcur[256];
    int b = blockIdx.x, t = threadIdx.x;
    int rstart = base[b * NPB];
    int rend = (b == NBK - 1) ? N_EDGES : base[(b + 1) * NPB];
    int wstart = ((rstart + 7) & ~7) + b * 2048;   // 8-aligned private write region
    lc[t] = 0;
    __syncthreads();
    for (int e = rstart + t; e < rend; e += 256) atomicAdd(&lc[(int)(ebuf[e] >> 20)], 1);
    __syncthreads();
    int v = lc[t];               // real degree
    int vp = (v + 7) & ~7;       // padded to multiple of 8
    ss[t] = vp;
    __syncthreads();
    for (int o = 1; o < 256; o <<= 1) {
        int a = (t >= o) ? ss[t - o] : 0;
        __syncthreads();
        ss[t] += a;
        __syncthreads();
    }
    lo[t] = ss[t] - vp;
    lcur[t] = 0;
    int node = b * 256 + t;
    if (node < n) {
        cnt[node] = vp;
        dinv[node] = rsqrtf((float)v + 1.0f);
        off[node] = wstart + lo[t];
    }
    __syncthreads();
    for (int e = rstart + t; e < rend; e += 256) {
        unsigned u = ebuf[e];
        int l = (int)(u >> 20);
        int p = atomicAdd(&lcur[l], 1);
        es[wstart + lo[l] + p] = (int)(u & 0xFFFFFu);
    }
    for (int q = v; q < vp; ++q) es[wstart + lo[t] + q] = N_NODES;
}

// ---------------- GEMM1 (MFMA hi/lo): hwb1 = bf16( dinv * (x[M,256] @ w1[256,64]) ) ----

__global__ __launch_bounds__(256) void k_gemm1_mfma(const float* __restrict__ x,
                                                    const float* __restrict__ w,
                                                    const float* __restrict__ dinv,
                                                    unsigned short* __restrict__ out, int M) {
    __shared__ unsigned short Bhi[32 * 64 * 8];   // 32 KB
    __shared__ unsigned short Blo[32 * 64 * 8];   // 32 KB
    int t = threadIdx.x;
    int wave = t >> 6, lane = t & 63;

    {
        int c = t & 63;
        int kg0 = t >> 6;
#pragma unroll
        for (int i = 0; i < 8; ++i) {
            int kgrp = kg0 + i * 4;
            bf16x8 h8, l8;
#pragma unroll
            for (int j = 0; j < 8; ++j) {
                float f = w[(size_t)(kgrp * 8 + j) * 64 + c];
                unsigned u = __float_as_uint(f);
                h8[j] = (short)(u >> 16);
                float l = f - __uint_as_float(u & 0xFFFF0000u);
                l8[j] = (short)(__float_as_uint(l) >> 16);
            }
            *(bf16x8*)&Bhi[(kgrp * 64 + c) * 8] = h8;
            *(bf16x8*)&Blo[(kgrp * 64 + c) * 8] = l8;
        }
    }
    __syncthreads();

    int row0w = blockIdx.x * 64 + wave * 16;
    int r = row0w + (lane & 15); if (r >= M) r = M - 1;
    const float* xr = x + (size_t)r * 256 + (lane >> 4) * 8;

    f32x4 acc[4] = {{0.f,0.f,0.f,0.f},{0.f,0.f,0.f,0.f},{0.f,0.f,0.f,0.f},{0.f,0.f,0.f,0.f}};

#pragma unroll
    for (int kf = 0; kf < 8; ++kf) {
        float4 a0 = *(const float4*)(xr + kf * 32);
        float4 a1 = *(const float4*)(xr + kf * 32 + 4);
        bf16x8 ahi, alo;
        split8(a0, a1, ahi, alo);
        int kgrpR = kf * 4 + (lane >> 4);
#pragma unroll
        for (int cf = 0; cf < 4; ++cf) {
            bf16x8 bhi = *(const bf16x8*)&Bhi[(kgrpR * 64 + cf * 16 + (lane & 15)) * 8];
            bf16x8 blo = *(const bf16x8*)&Blo[(kgrpR * 64 + cf * 16 + (lane & 15)) * 8];
            acc[cf] = __builtin_amdgcn_mfma_f32_16x16x32_bf16(ahi, bhi, acc[cf], 0, 0, 0);
            acc[cf] = __builtin_amdgcn_mfma_f32_16x16x32_bf16(ahi, blo, acc[cf], 0, 0, 0);
            acc[cf] = __builtin_amdgcn_mfma_f32_16x16x32_bf16(alo, bhi, acc[cf], 0, 0, 0);
        }
    }

#pragma unroll
    for (int j = 0; j < 4; ++j) {
        int rr = row0w + (lane >> 4) * 4 + j;
        if (rr < M) {
            float s = dinv[rr];
#pragma unroll
            for (int cf = 0; cf < 4; ++cf)
                out[(size_t)rr * 64 + cf * 16 + (lane & 15)] = f2b(acc[cf][j] * s);
        }
    }
}

// ---------------- fused agg1 + GEMM2: hwb2 = bf16( dinv * (relu-agg(hwb1) @ w2) ) ------
// block = 16 nodes (4 waves x 4 sequential nodes). Gather phase: wave-per-node,
// lane = channel, scalar 2B gathers (8 outstanding). h1 rows staged in LDS fp32.
// MFMA phase: waves 0/1 compute 16x32 = h1tile @ w2 (hi/lo split), write bf16.

__global__ __launch_bounds__(256) void k_agg1_gemm2(const unsigned short* __restrict__ hwb,
                                                    const float* __restrict__ dinv,
                                                    const int* __restrict__ cnt,
                                                    const int* __restrict__ off,
                                                    const int* __restrict__ es,
                                                    const float* __restrict__ bias,
                                                    const float* __restrict__ w2,
                                                    unsigned short* __restrict__ out) {
    __shared__ float hs[16][68];     // 16 h1 rows, padded (stride 68 -> 2-way banks)
    int t = threadIdx.x;
    int wv = t >> 6, lane = t & 63;
    int node0 = blockIdx.x * 16;
    float bl = bias[lane];

#pragma unroll
    for (int i = 0; i < 4; ++i) {
        int node = node0 + wv * 4 + i;
        float dn = dinv[node];
        float acc0 = b2f(hwb[(size_t)node * 64 + lane]);   // self (pre-scaled)
        float acc1 = 0.0f;
        const int* ep = es + off[node];
        int mp = cnt[node];
        for (int j = 0; j < mp; j += 8) {
            int4 e0 = *(const int4*)&ep[j];
            int4 e1 = *(const int4*)&ep[j + 4];
            float v0 = b2f(hwb[(size_t)e0.x * 64 + lane]);
            float v1 = b2f(hwb[(size_t)e0.y * 64 + lane]);
            float v2 = b2f(hwb[(size_t)e0.z * 64 + lane]);
            float v3 = b2f(hwb[(size_t)e0.w * 64 + lane]);
            float v4 = b2f(hwb[(size_t)e1.x * 64 + lane]);
            float v5 = b2f(hwb[(size_t)e1.y * 64 + lane]);
            float v6 = b2f(hwb[(size_t)e1.z * 64 + lane]);
            float v7 = b2f(hwb[(size_t)e1.w * 64 + lane]);
            acc0 += (v0 + v1) + (v2 + v3);
            acc1 += (v4 + v5) + (v6 + v7);
        }
        hs[wv * 4 + i][lane] = fmaxf(fmaf(dn, acc0 + acc1, bl), 0.0f);
    }
    __syncthreads();

    if (wv < 2) {
        int colbase = wv * 16;
        int r = lane & 15;           // A row / B col / C col
        int kg = lane >> 4;          // k-group 0..3
        f32x4 acc = {0.f, 0.f, 0.f, 0.f};
#pragma unroll
        for (int ks = 0; ks < 2; ++ks) {
            float a[8], b[8];
#pragma unroll
            for (int j = 0; j < 8; ++j) {
                int k = ks * 32 + kg * 8 + j;
                a[j] = hs[r][k];
                b[j] = w2[(size_t)k * 32 + colbase + r];
            }
            bf16x8 ahi, alo, bhi, blo;
            split8a(a, ahi, alo);
            split8a(b, bhi, blo);
            acc = __builtin_amdgcn_mfma_f32_16x16x32_bf16(ahi, bhi, acc, 0, 0, 0);
            acc = __builtin_amdgcn_mfma_f32_16x16x32_bf16(ahi, blo, acc, 0, 0, 0);
            acc = __builtin_amdgcn_mfma_f32_16x16x32_bf16(alo, bhi, acc, 0, 0, 0);
        }
#pragma unroll
        for (int reg = 0; reg < 4; ++reg) {
            int row = kg * 4 + reg;
            int nd = node0 + row;
            out[(size_t)nd * 32 + colbase + r] = f2b(acc[reg] * dinv[nd]);
        }
    }
}

// ---------------- agg layer 2 + fused MLP head (round-5 proven form) ------------------
// per block: 8 nodes x 32 feats (half-wave per node); h2 kept in LDS

__global__ __launch_bounds__(256) void k_agg2_mlp(const unsigned short* __restrict__ hwb,
                                                  const float* __restrict__ dinv,
                                                  const int* __restrict__ cnt,
                                                  const int* __restrict__ off,
                                                  const int* __restrict__ es,
                                                  const float* __restrict__ bias2,
                                                  const float* __restrict__ wf1,
                                                  const float* __restrict__ bf1,
                                                  const float* __restrict__ wf2,
                                                  const float* __restrict__ bf2,
                                                  float* __restrict__ out) {
    __shared__ float hs[8][33];
    __shared__ float W1[512];
    __shared__ float B1[16];
    __shared__ float W2[16];
    int t = threadIdx.x;
    W1[t] = wf1[t];
    W1[t + 256] = wf1[t + 256];
    if (t < 16) { B1[t] = bf1[t]; W2[t] = wf2[t]; }

    int node0 = blockIdx.x * 8;
    int nl = t >> 5;            // local node 0..7
    int c = t & 31;
    int node = node0 + nl;
    float dn = dinv[node];
    float acc0 = b2f(hwb[(size_t)node * 32 + c]);
    float acc1 = 0.0f;
    const int* ep = es + off[node];
    int mp = cnt[node];
    for (int j = 0; j < mp; j += 8) {
        int4 e0 = *(const int4*)&ep[j];
        int4 e1 = *(const int4*)&ep[j + 4];
        float v0 = b2f(hwb[(size_t)e0.x * 32 + c]);
        float v1 = b2f(hwb[(size_t)e0.y * 32 + c]);
        float v2 = b2f(hwb[(size_t)e0.z * 32 + c]);
        float v3 = b2f(hwb[(size_t)e0.w * 32 + c]);
        float v4 = b2f(hwb[(size_t)e1.x * 32 + c]);
        float v5 = b2f(hwb[(size_t)e1.y * 32 + c]);
        float v6 = b2f(hwb[(size_t)e1.z * 32 + c]);
        float v7 = b2f(hwb[(size_t)e1.w * 32 + c]);
        acc0 += (v0 + v1) + (v2 + v3);
        acc1 += (v4 + v5) + (v6 + v7);
    }
    hs[nl][c] = fmaxf(fmaf(dn, acc0 + acc1, bias2[c]), 0.0f);
    __syncthreads();
    if (t < 128) {
        int nn = t >> 4, jj = t & 15;
        float s = B1[jj];
#pragma unroll
        for (int k = 0; k < 32; ++k) s += hs[nn][k] * W1[k * 16 + jj];
        float p = fmaxf(s, 0.0f) * W2[jj];
        p += __shfl_xor(p, 1);
        p += __shfl_xor(p, 2);
        p += __shfl_xor(p, 4);
        p += __shfl_xor(p, 8);
        if (jj == 0) out[node0 + nn] = p + bf2[0];
    }
}

// ---------------- host ----------------

extern "C" void kernel_launch(void* const* d_in, const int* in_sizes, int n_in,
                              void* d_out, int out_size, void* d_ws, size_t ws_size,
                              hipStream_t stream) {
    const float* x   = (const float*)d_in[0];
    const int*   ei  = (const int*)d_in[1];
    const float* w1  = (const float*)d_in[2];
    const float* b1  = (const float*)d_in[3];
    const float* w2  = (const float*)d_in[4];
    const float* b2  = (const float*)d_in[5];
    const float* wf1 = (const float*)d_in[6];
    const float* bf1 = (const float*)d_in[7];
    const float* wf2 = (const float*)d_in[8];
    const float* bf2 = (const float*)d_in[9];

    const int n = N_NODES;
    const int E = N_EDGES;
    const int* srcp = ei;        // edge_index[0]
    const int* dstp = ei + E;    // edge_index[1]

    char* p = (char*)d_ws;
    auto take = [&](size_t bytes) {
        char* r = p;
        p += (bytes + 255) & ~(size_t)255;
        return r;
    };
    float* dinv = (float*)take((size_t)n * 4);
    int*   cnt  = (int*)take((size_t)n * 4);
    int*   off  = (int*)take((size_t)n * 4);
    int*   gcnt = (int*)take((size_t)NSLOT * 4);
    int*   bsum = (int*)take(512);
    int*   es   = (int*)take((size_t)ES_CAP * 4);
    unsigned short* hwb1 = (unsigned short*)take((size_t)(n + 1) * 64 * 2);  // aliases ebuf
    unsigned short* hwb2 = (unsigned short*)take((size_t)(n + 1) * 32 * 2);
    unsigned* ebuf = (unsigned*)hwb1;   // 6.4MB, consumed by k_bucket_csr before gemm1

    // build per-node padded CSR (bucketed two-phase, no global atomics)
    k_hist<<<NPB, 256, 0, stream>>>(dstp, gcnt, hwb1, hwb2, E);
    k_scanA<<<NSB, 1024, 0, stream>>>(gcnt, bsum, NSLOT);
    k_scanC<<<NSB, 1024, 0, stream>>>(gcnt, bsum, NSLOT);
    k_partition<<<NPB, 256, 0, stream>>>(srcp, dstp, gcnt, ebuf, E);
    k_bucket_csr<<<NBK, 256, 0, stream>>>(gcnt, ebuf, cnt, dinv, off, es, n);

    // GNN layers
    k_gemm1_mfma<<<(n + 63) / 64, 256, 0, stream>>>(x, w1, dinv, hwb1, n);
    k_agg1_gemm2<<<n / 16, 256, 0, stream>>>(hwb1, dinv, cnt, off, es, b1, w2, hwb2);
    k_agg2_mlp<<<n / 8, 256, 0, stream>>>(hwb2, dinv, cnt, off, es, b2,
                                          wf1, bf1, wf2, bf2, (float*)d_out);
}

// Round 10
// 161.075 us; speedup vs baseline: 1.8161x; 1.0195x over previous
//
#include <hip/hip_runtime.h>
#include <cstdint>
#include <cstddef>

#define N_NODES 100000
#define N_EDGES 1600000

#define NBK   391                          // ceil(100000/256) buckets of 256 nodes
#define NPB   256                          // partition blocks
#define EPB   ((N_EDGES + NPB - 1) / NPB)  // 6250 edges per partition block
#define NSLOT (NBK * NPB)                  // 100096 (bucket-major: slot = b*NPB + bid)
#define NSB   ((NSLOT + 1023) / 1024)      // 98 scan blocks
#define ES_CAP (N_EDGES + NBK * 2048 + 64) // padded edge-list capacity
#define EB_CAP 5120                        // LDS stage cap per bucket (mean 4096, sd 64)

typedef __attribute__((ext_vector_type(8))) short bf16x8;
typedef __attribute__((ext_vector_type(4))) float f32x4;

__device__ __forceinline__ float b2f(unsigned short u) {
    return __uint_as_float(((unsigned)u) << 16);
}
__device__ __forceinline__ unsigned short f2b(float f) {
    unsigned x = __float_as_uint(f);
    return (unsigned short)((x + 0x7FFFu + ((x >> 16) & 1u)) >> 16);
}

// split 8 f32 -> bf16 hi (trunc) + bf16 lo (trunc of exact residual)
__device__ __forceinline__ void split8a(const float* f, bf16x8& hi, bf16x8& lo) {
#pragma unroll
    for (int j = 0; j < 8; ++j) {
        unsigned u = __float_as_uint(f[j]);
        hi[j] = (short)(u >> 16);
        float l = f[j] - __uint_as_float(u & 0xFFFF0000u);   // exact
        lo[j] = (short)(__float_as_uint(l) >> 16);
    }
}
__device__ __forceinline__ void split8(const float4& a0, const float4& a1,
                                       bf16x8& hi, bf16x8& lo) {
    float f[8] = {a0.x, a0.y, a0.z, a0.w, a1.x, a1.y, a1.z, a1.w};
    split8a(f, hi, lo);
}

// ---------------- build: bucket partition with private sub-regions ----------------

// also zeroes the sentinel rows (row N_NODES) of both bf16 operand buffers (block 0)
__global__ __launch_bounds__(256) void k_hist(const int* __restrict__ dst,
                                              int* __restrict__ gcnt,
                                              unsigned short* __restrict__ hwb1,
                                              unsigned short* __restrict__ hwb2, int E) {
    __shared__ int lh[NBK];
    int t = threadIdx.x, bid = blockIdx.x;
    if (bid == 0) {
        if (t < 64) hwb1[(size_t)N_NODES * 64 + t] = 0;
        else if (t < 96) hwb2[(size_t)N_NODES * 32 + (t - 64)] = 0;
    }
    for (int i = t; i < NBK; i += 256) lh[i] = 0;
    __syncthreads();
    int e0 = bid * EPB, e1 = min(E, e0 + EPB);
    for (int e = e0 + t; e < e1; e += 256) atomicAdd(&lh[dst[e] >> 8], 1);
    __syncthreads();
    for (int b = t; b < NBK; b += 256) gcnt[b * NPB + bid] = lh[b];
}

// per-scan-block local exclusive scan; bsum[blk] = block total (NOT globally corrected;
// consumers add the bsum prefix themselves)
__global__ __launch_bounds__(1024) void k_scanA(int* __restrict__ g,
                                                int* __restrict__ bsum, int ntot) {
    __shared__ int s[1024];
    int t = threadIdx.x;
    int i = blockIdx.x * 1024 + t;
    int v = (i < ntot) ? g[i] : 0;
    s[t] = v;
    __syncthreads();
    for (int o = 1; o < 1024; o <<= 1) {
        int a = (t >= o) ? s[t - o] : 0;
        __syncthreads();
        s[t] += a;
        __syncthreads();
    }
    if (i < ntot) g[i] = s[t] - v;
    if (t == 1023) bsum[blockIdx.x] = s[1023];
}

// compute exclusive prefix of bsum[0..NSB) into pe[] (first 128 threads)
__device__ __forceinline__ void bsum_prefix(const int* __restrict__ bsum, int* pe) {
    int t = threadIdx.x;
    if (t < 128) {
        int v = (t < NSB) ? bsum[t] : 0;
        pe[t] = v;
    }
    __syncthreads();
    if (t < 128) {
        int v = pe[t];
        int acc = v;
#pragma unroll
        for (int o = 1; o < 128; o <<= 1) {
            int a = (t >= o) ? pe[t - o] : 0;
            __syncthreads();
            if (t < 128) pe[t] = acc = acc + a;
            __syncthreads();
        }
        pe[t] = acc - v;   // exclusive
    }
    __syncthreads();
}

__global__ __launch_bounds__(256) void k_partition(const int* __restrict__ src,
                                                   const int* __restrict__ dst,
                                                   const int* __restrict__ g,
                                                   const int* __restrict__ bsum,
                                                   unsigned* __restrict__ ebuf, int E) {
    __shared__ int lcur[NBK];
    __shared__ int pe[128];
    int t = threadIdx.x, bid = blockIdx.x;
    // exclusive prefix of bsum (all threads participate in barriers)
    {
        int v = 0;
        if (t < 128) { v = (t < NSB) ? bsum[t] : 0; pe[t] = v; }
        __syncthreads();
        for (int o = 1; o < 128; o <<= 1) {
            int a = 0;
            if (t < 128 && t >= o) a = pe[t - o];
            __syncthreads();
            if (t < 128) pe[t] += a;
            __syncthreads();
        }
        if (t < 128) pe[t] -= v;
        __syncthreads();
    }
    for (int b = t; b < NBK; b += 256) {
        int slot = b * NPB + bid;
        lcur[b] = g[slot] + pe[slot >> 10];
    }
    __syncthreads();
    int e0 = bid * EPB, e1 = min(E, e0 + EPB);
    for (int e = e0 + t; e < e1; e += 256) {
        int d = dst[e];
        int b = d >> 8;
        int p = atomicAdd(&lcur[b], 1);
        ebuf[p] = (unsigned)src[e] | ((unsigned)(d & 255) << 20);
    }
}

// one block per bucket: stage bucket edges in LDS, per-node count/scan/place
// -> 8-padded per-node CSR (pad slots = sentinel src N_NODES, a zero row in hwb)
__global__ __launch_bounds__(256) void k_bucket_csr(const int* __restrict__ g,
                                                    const int* __restrict__ bsum,
                                                    const unsigned* __restrict__ ebuf,
                                                    int* __restrict__ cnt,
                                                    float* __restrict__ dinv,
                                                    int* __restrict__ off,
                                                    int* __restrict__ es, int n) {
    __shared__ unsigned eb[EB_CAP];
    __shared__ int lc[256];
    __shared__ int ss[256];
    __shared__ int lo[256];
    __shared__ int lcur[256];
    __shared__ int pe[128];
    int b = blockIdx.x, t = threadIdx.x;
    // exclusive prefix of bsum
    {
        int v = 0;
        if (t < 128) { v = (t < NSB) ? bsum[t] : 0; pe[t] = v; }
        __syncthreads();
        for (int o = 1; o < 128; o <<= 1) {
            int a = 0;
            if (t < 128 && t >= o) a = pe[t - o];
            __syncthreads();
            if (t < 128) pe[t] += a;
            __syncthreads();
        }
        if (t < 128) pe[t] -= v;
        __syncthreads();
    }
    int s0 = b * NPB;
    int rstart = g[s0] + pe[s0 >> 10];
    int rend;
    if (b == NBK - 1) rend = N_EDGES;
    else { int s1 = (b + 1) * NPB; rend = g[s1] + pe[s1 >> 10]; }
    int m = rend - rstart;
    int ms = min(m, EB_CAP);
    int wstart = ((rstart + 7) & ~7) + b * 2048;   // 8-aligned private write region
    // stage + zero counters
    lc[t] = 0;
    for (int i = t; i < ms; i += 256) eb[i] = ebuf[rstart + i];
    __syncthreads();
    for (int e = t; e < m; e += 256) {
        unsigned u = (e < ms) ? eb[e] : ebuf[rstart + e];
        atomicAdd(&lc[(int)(u >> 20)], 1);
    }
    __syncthreads();
    int v = lc[t];               // real degree
    int vp = (v + 7) & ~7;       // padded to multiple of 8
    ss[t] = vp;
    __syncthreads();
    for (int o = 1; o < 256; o <<= 1) {
        int a = (t >= o) ? ss[t - o] : 0;
        __syncthreads();
        ss[t] += a;
        __syncthreads();
    }
    lo[t] = ss[t] - vp;
    lcur[t] = 0;
    int node = b * 256 + t;
    if (node < n) {
        cnt[node] = vp;
        dinv[node] = rsqrtf((float)v + 1.0f);
        off[node] = wstart + lo[t];
    }
    __syncthreads();
    for (int e = t; e < m; e += 256) {
        unsigned u = (e < ms) ? eb[e] : ebuf[rstart + e];
        int l = (int)(u >> 20);
        int p = atomicAdd(&lcur[l], 1);
        es[wstart + lo[l] + p] = (int)(u & 0xFFFFFu);
    }
    for (int q = v; q < vp; ++q) es[wstart + lo[t] + q] = N_NODES;
}

// ---------------- GEMM1 (MFMA hi/lo): hwb1 = bf16( dinv * (x[M,256] @ w1[256,64]) ) ----

__global__ __launch_bounds__(256) void k_gemm1_mfma(const float* __restrict__ x,
                                                    const float* __restrict__ w,
                                                    const float* __restrict__ dinv,
                                                    unsigned short* __restrict__ out, int M) {
    __shared__ unsigned short Bhi[32 * 64 * 8];   // 32 KB
    __shared__ unsigned short Blo[32 * 64 * 8];   // 32 KB
    int t = threadIdx.x;
    int wave = t >> 6, lane = t & 63;

    {
        int c = t & 63;
        int kg0 = t >> 6;
#pragma unroll
        for (int i = 0; i < 8; ++i) {
            int kgrp = kg0 + i * 4;
            bf16x8 h8, l8;
#pragma unroll
            for (int j = 0; j < 8; ++j) {
                float f = w[(size_t)(kgrp * 8 + j) * 64 + c];
                unsigned u = __float_as_uint(f);
                h8[j] = (short)(u >> 16);
                float l = f - __uint_as_float(u & 0xFFFF0000u);
                l8[j] = (short)(__float_as_uint(l) >> 16);
            }
            *(bf16x8*)&Bhi[(kgrp * 64 + c) * 8] = h8;
            *(bf16x8*)&Blo[(kgrp * 64 + c) * 8] = l8;
        }
    }
    __syncthreads();

    int row0w = blockIdx.x * 64 + wave * 16;
    int r = row0w + (lane & 15); if (r >= M) r = M - 1;
    const float* xr = x + (size_t)r * 256 + (lane >> 4) * 8;

    f32x4 acc[4] = {{0.f,0.f,0.f,0.f},{0.f,0.f,0.f,0.f},{0.f,0.f,0.f,0.f},{0.f,0.f,0.f,0.f}};

#pragma unroll
    for (int kf = 0; kf < 8; ++kf) {
        float4 a0 = *(const float4*)(xr + kf * 32);
        float4 a1 = *(const float4*)(xr + kf * 32 + 4);
        bf16x8 ahi, alo;
        split8(a0, a1, ahi, alo);
        int kgrpR = kf * 4 + (lane >> 4);
#pragma unroll
        for (int cf = 0; cf < 4; ++cf) {
            bf16x8 bhi = *(const bf16x8*)&Bhi[(kgrpR * 64 + cf * 16 + (lane & 15)) * 8];
            bf16x8 blo = *(const bf16x8*)&Blo[(kgrpR * 64 + cf * 16 + (lane & 15)) * 8];
            acc[cf] = __builtin_amdgcn_mfma_f32_16x16x32_bf16(ahi, bhi, acc[cf], 0, 0, 0);
            acc[cf] = __builtin_amdgcn_mfma_f32_16x16x32_bf16(ahi, blo, acc[cf], 0, 0, 0);
            acc[cf] = __builtin_amdgcn_mfma_f32_16x16x32_bf16(alo, bhi, acc[cf], 0, 0, 0);
        }
    }

#pragma unroll
    for (int j = 0; j < 4; ++j) {
        int rr = row0w + (lane >> 4) * 4 + j;
        if (rr < M) {
            float s = dinv[rr];
#pragma unroll
            for (int cf = 0; cf < 4; ++cf)
                out[(size_t)rr * 64 + cf * 16 + (lane & 15)] = f2b(acc[cf][j] * s);
        }
    }
}

// ---------------- fused agg1 + GEMM2: hwb2 = bf16( dinv * (relu-agg(hwb1) @ w2) ) ------
// block = 16 nodes (4 waves x 4 INTERLEAVED nodes -> up to 32 outstanding gathers).
// Gather: lane = channel, scalar 2B gathers. h1 rows staged in LDS fp32.
// MFMA phase: waves 0/1 compute 16x32 = h1tile @ w2 (hi/lo split), write bf16.

__global__ __launch_bounds__(256) void k_agg1_gemm2(const unsigned short* __restrict__ hwb,
                                                    const float* __restrict__ dinv,
                                                    const int* __restrict__ cnt,
                                                    const int* __restrict__ off,
                                                    const int* __restrict__ es,
                                                    const float* __restrict__ bias,
                                                    const float* __restrict__ w2,
                                                    unsigned short* __restrict__ out) {
    __shared__ float hs[16][68];     // 16 h1 rows, padded (stride 68 -> 2-way banks)
    int t = threadIdx.x;
    int wv = t >> 6, lane = t & 63;
    int node0 = blockIdx.x * 16;
    float bl = bias[lane];

    float dn[4], a0[4], a1[4];
    const int* ep[4];
    int mp[4];
#pragma unroll
    for (int i = 0; i < 4; ++i) {
        int node = node0 + wv * 4 + i;
        dn[i] = dinv[node];
        a0[i] = b2f(hwb[(size_t)node * 64 + lane]);   // self (pre-scaled)
        a1[i] = 0.0f;
        ep[i] = es + off[node];
        mp[i] = cnt[node];
    }
    int mmax = max(max(mp[0], mp[1]), max(mp[2], mp[3]));
    for (int j = 0; j < mmax; j += 8) {
#pragma unroll
        for (int i = 0; i < 4; ++i) {
            if (j < mp[i]) {   // wave-uniform
                int4 e0 = *(const int4*)&ep[i][j];
                int4 e1 = *(const int4*)&ep[i][j + 4];
                float v0 = b2f(hwb[(size_t)e0.x * 64 + lane]);
                float v1 = b2f(hwb[(size_t)e0.y * 64 + lane]);
                float v2 = b2f(hwb[(size_t)e0.z * 64 + lane]);
                float v3 = b2f(hwb[(size_t)e0.w * 64 + lane]);
                float v4 = b2f(hwb[(size_t)e1.x * 64 + lane]);
                float v5 = b2f(hwb[(size_t)e1.y * 64 + lane]);
                float v6 = b2f(hwb[(size_t)e1.z * 64 + lane]);
                float v7 = b2f(hwb[(size_t)e1.w * 64 + lane]);
                a0[i] += (v0 + v1) + (v2 + v3);
                a1[i] += (v4 + v5) + (v6 + v7);
            }
        }
    }
#pragma unroll
    for (int i = 0; i < 4; ++i)
        hs[wv * 4 + i][lane] = fmaxf(fmaf(dn[i], a0[i] + a1[i], bl), 0.0f);
    __syncthreads();

    if (wv < 2) {
        int colbase = wv * 16;
        int r = lane & 15;           // A row / B col / C col
        int kg = lane >> 4;          // k-group 0..3
        f32x4 acc = {0.f, 0.f, 0.f, 0.f};
#pragma unroll
        for (int ks = 0; ks < 2; ++ks) {
            float a[8], b[8];
#pragma unroll
            for (int j = 0; j < 8; ++j) {
                int k = ks * 32 + kg * 8 + j;
                a[j] = hs[r][k];
                b[j] = w2[(size_t)k * 32 + colbase + r];
            }
            bf16x8 ahi, alo, bhi, blo;
            split8a(a, ahi, alo);
            split8a(b, bhi, blo);
            acc = __builtin_amdgcn_mfma_f32_16x16x32_bf16(ahi, bhi, acc, 0, 0, 0);
            acc = __builtin_amdgcn_mfma_f32_16x16x32_bf16(ahi, blo, acc, 0, 0, 0);
            acc = __builtin_amdgcn_mfma_f32_16x16x32_bf16(alo, bhi, acc, 0, 0, 0);
        }
#pragma unroll
        for (int reg = 0; reg < 4; ++reg) {
            int row = kg * 4 + reg;
            int nd = node0 + row;
            out[(size_t)nd * 32 + colbase + r] = f2b(acc[reg] * dinv[nd]);
        }
    }
}

// ---------------- agg layer 2 + fused MLP head ------------------

__global__ __launch_bounds__(256) void k_agg2_mlp(const unsigned short* __restrict__ hwb,
                                                  const float* __restrict__ dinv,
                                                  const int* __restrict__ cnt,
                                                  const int* __restrict__ off,
                                                  const int* __restrict__ es,
                                                  const float* __restrict__ bias2,
                                                  const float* __restrict__ wf1,
                                                  const float* __restrict__ bf1,
                                                  const float* __restrict__ wf2,
                                                  const float* __restrict__ bf2,
                                                  float* __restrict__ out) {
    __shared__ float hs[8][33];
    __shared__ float W1[512];
    __shared__ float B1[16];
    __shared__ float W2[16];
    int t = threadIdx.x;
    W1[t] = wf1[t];
    W1[t + 256] = wf1[t + 256];
    if (t < 16) { B1[t] = bf1[t]; W2[t] = wf2[t]; }

    int node0 = blockIdx.x * 8;
    int nl = t >> 5;            // local node 0..7
    int c = t & 31;
    int node = node0 + nl;
    float dn = dinv[node];
    float acc0 = b2f(hwb[(size_t)node * 32 + c]);
    float acc1 = 0.0f;
    const int* ep = es + off[node];
    int mp = cnt[node];
    for (int j = 0; j < mp; j += 8) {
        int4 e0 = *(const int4*)&ep[j];
        int4 e1 = *(const int4*)&ep[j + 4];
        float v0 = b2f(hwb[(size_t)e0.x * 32 + c]);
        float v1 = b2f(hwb[(size_t)e0.y * 32 + c]);
        float v2 = b2f(hwb[(size_t)e0.z * 32 + c]);
        float v3 = b2f(hwb[(size_t)e0.w * 32 + c]);
        float v4 = b2f(hwb[(size_t)e1.x * 32 + c]);
        float v5 = b2f(hwb[(size_t)e1.y * 32 + c]);
        float v6 = b2f(hwb[(size_t)e1.z * 32 + c]);
        float v7 = b2f(hwb[(size_t)e1.w * 32 + c]);
        acc0 += (v0 + v1) + (v2 + v3);
        acc1 += (v4 + v5) + (v6 + v7);
    }
    hs[nl][c] = fmaxf(fmaf(dn, acc0 + acc1, bias2[c]), 0.0f);
    __syncthreads();
    if (t < 128) {
        int nn = t >> 4, jj = t & 15;
        float s = B1[jj];
#pragma unroll
        for (int k = 0; k < 32; ++k) s += hs[nn][k] * W1[k * 16 + jj];
        float p = fmaxf(s, 0.0f) * W2[jj];
        p += __shfl_xor(p, 1);
        p += __shfl_xor(p, 2);
        p += __shfl_xor(p, 4);
        p += __shfl_xor(p, 8);
        if (jj == 0) out[node0 + nn] = p + bf2[0];
    }
}

// ---------------- host ----------------

extern "C" void kernel_launch(void* const* d_in, const int* in_sizes, int n_in,
                              void* d_out, int out_size, void* d_ws, size_t ws_size,
                              hipStream_t stream) {
    const float* x   = (const float*)d_in[0];
    const int*   ei  = (const int*)d_in[1];
    const float* w1  = (const float*)d_in[2];
    const float* b1  = (const float*)d_in[3];
    const float* w2  = (const float*)d_in[4];
    const float* b2  = (const float*)d_in[5];
    const float* wf1 = (const float*)d_in[6];
    const float* bf1 = (const float*)d_in[7];
    const float* wf2 = (const float*)d_in[8];
    const float* bf2 = (const float*)d_in[9];

    const int n = N_NODES;
    const int E = N_EDGES;
    const int* srcp = ei;        // edge_index[0]
    const int* dstp = ei + E;    // edge_index[1]

    char* p = (char*)d_ws;
    auto take = [&](size_t bytes) {
        char* r = p;
        p += (bytes + 255) & ~(size_t)255;
        return r;
    };
    float* dinv = (float*)take((size_t)n * 4);
    int*   cnt  = (int*)take((size_t)n * 4);
    int*   off  = (int*)take((size_t)n * 4);
    int*   gcnt = (int*)take((size_t)NSLOT * 4);
    int*   bsum = (int*)take(512);
    int*   es   = (int*)take((size_t)ES_CAP * 4);
    unsigned short* hwb1 = (unsigned short*)take((size_t)(n + 1) * 64 * 2);  // aliases ebuf
    unsigned short* hwb2 = (unsigned short*)take((size_t)(n + 1) * 32 * 2);
    unsigned* ebuf = (unsigned*)hwb1;   // 6.4MB, consumed by k_bucket_csr before gemm1

    // build per-node padded CSR (bucketed two-phase, no global atomics)
    k_hist<<<NPB, 256, 0, stream>>>(dstp, gcnt, hwb1, hwb2, E);
    k_scanA<<<NSB, 1024, 0, stream>>>(gcnt, bsum, NSLOT);
    k_partition<<<NPB, 256, 0, stream>>>(srcp, dstp, gcnt, bsum, ebuf, E);
    k_bucket_csr<<<NBK, 256, 0, stream>>>(gcnt, bsum, ebuf, cnt, dinv, off, es, n);

    // GNN layers
    k_gemm1_mfma<<<(n + 63) / 64, 256, 0, stream>>>(x, w1, dinv, hwb1, n);
    k_agg1_gemm2<<<n / 16, 256, 0, stream>>>(hwb1, dinv, cnt, off, es, b1, w2, hwb2);
    k_agg2_mlp<<<n / 8, 256, 0, stream>>>(hwb2, dinv, cnt, off, es, b2,
                                          wf1, bf1, wf2, bf2, (float*)d_out);
}